// Round 3
// baseline (328.305 us; speedup 1.0000x reference)
//
#include <hip/hip_runtime.h>
#include <cstdint>

#define B_SZ   4
#define E_DIM  16
#define C_INST 24
#define HW_N   262144   // 512*512

#define DELTA_VAR  0.75f
#define DELTA_DIST 2.0f
#define ALPHA_W 1.0f
#define BETA_W  1.0f
#define GAMMA_W 0.001f

#define P1_BLOCKS 48                      // blocks per (egroup, batch)
#define P1_GROUPS (HW_N / 4)              // 65536 float4 pixel-groups
#define P1_COMBO_THREADS (P1_BLOCKS * 256)        // 12288
#define P1_ITERS ((P1_GROUPS + P1_COMBO_THREADS - 1) / P1_COMBO_THREADS)  // 6

// ---------------------------------------------------------------------------
// Pass 1: segment sums. Each block owns 2 embedding dims (acc[2][24] = 48
// VGPRs -> 6 waves/SIMD with __launch_bounds__(256,6)). 4 pixels per thread
// per iteration via int4/float4 loads. Counts via __ballot -> SGPR adds
// (no extra VGPR cost, SALU pipe). Epilogue: 6-step butterfly + LDS stage +
// 48 global fp32 atomics per block.
// ---------------------------------------------------------------------------
__global__ __launch_bounds__(256, 6) void pass1_kernel(
    const float* __restrict__ input, const int* __restrict__ target,
    float* __restrict__ sums, float* __restrict__ counts)
{
    const int tid  = threadIdx.x;
    const int lane = tid & 63;
    const int wv   = tid >> 6;
    const int eg   = blockIdx.y;          // 0..7 -> dims eg*2, eg*2+1
    const int b    = blockIdx.z;

    const float4* __restrict__ s0 =
        (const float4*)(input + ((size_t)b * E_DIM + eg * 2) * HW_N);
    const float4* __restrict__ s1 =
        (const float4*)(input + ((size_t)b * E_DIM + eg * 2 + 1) * HW_N);
    const int4* __restrict__ tgt4 = (const int4*)(target + (size_t)b * HW_N);

    float acc0[C_INST], acc1[C_INST];
    #pragma unroll
    for (int c = 0; c < C_INST; ++c) { acc0[c] = 0.f; acc1[c] = 0.f; }
    int scnt[C_INST];
    #pragma unroll
    for (int c = 0; c < C_INST; ++c) scnt[c] = 0;

    #pragma unroll
    for (int it = 0; it < P1_ITERS; ++it) {
        const int g = it * P1_COMBO_THREADS + blockIdx.x * 256 + tid;
        if (g < P1_GROUPS) {
            const int4   lab4 = tgt4[g];
            const float4 x0   = s0[g];
            const float4 x1   = s1[g];
            const int*   lp = &lab4.x;
            const float* a0 = &x0.x;
            const float* a1 = &x1.x;
            #pragma unroll
            for (int p = 0; p < 4; ++p) {
                const int   lab = lp[p];
                const float xa  = a0[p];
                const float xb  = a1[p];
                #pragma unroll
                for (int c = 0; c < C_INST; ++c) {
                    const float sel = (lab == c) ? 1.f : 0.f;
                    acc0[c] = fmaf(sel, xa, acc0[c]);
                    acc1[c] = fmaf(sel, xb, acc1[c]);
                }
                if (eg == 0) {   // uniform branch; counts on SALU via ballot
                    #pragma unroll
                    for (int c = 0; c < C_INST; ++c)
                        scnt[c] += (int)__popcll(__ballot(lab == c));
                }
            }
        }
    }

    // 64-lane butterfly reduction
    #pragma unroll
    for (int c = 0; c < C_INST; ++c) {
        #pragma unroll
        for (int m = 1; m < 64; m <<= 1) {
            acc0[c] += __shfl_xor(acc0[c], m, 64);
            acc1[c] += __shfl_xor(acc1[c], m, 64);
        }
    }

    __shared__ float red[4][2 * C_INST];
    __shared__ float redc[4][C_INST];
    if (lane == 0) {
        #pragma unroll
        for (int c = 0; c < C_INST; ++c) {
            red[wv][c]          = acc0[c];
            red[wv][C_INST + c] = acc1[c];
        }
        if (eg == 0) {
            #pragma unroll
            for (int c = 0; c < C_INST; ++c) redc[wv][c] = (float)scnt[c];
        }
    }
    __syncthreads();

    if (tid < 2 * C_INST) {
        const int el = tid / C_INST, c = tid % C_INST;
        const float s = red[0][tid] + red[1][tid] + red[2][tid] + red[3][tid];
        unsafeAtomicAdd(&sums[((size_t)b * C_INST + c) * E_DIM + eg * 2 + el], s);
    }
    if (eg == 0 && tid < C_INST) {
        const float s = redc[0][tid] + redc[1][tid] + redc[2][tid] + redc[3][tid];
        unsafeAtomicAdd(&counts[b * C_INST + tid], s);
    }
}

// ---------------------------------------------------------------------------
// Pass 2: hinged distance to own mean. One float4 pixel-group per thread
// (1024 blocks, low VGPR -> high occupancy, single memory wait per thread).
// mu in LDS [e][c]; hinge^2 scattered via register compare-chain.
// ---------------------------------------------------------------------------
__global__ __launch_bounds__(256, 8) void pass2_kernel(
    const float* __restrict__ input, const int* __restrict__ target,
    const float* __restrict__ sums, const float* __restrict__ counts,
    float* __restrict__ vars)
{
    __shared__ float mu_l[E_DIM][C_INST];
    const int tid  = threadIdx.x;
    const int lane = tid & 63;
    const int wv   = tid >> 6;
    const int b    = blockIdx.y;

    for (int i = tid; i < E_DIM * C_INST; i += 256) {
        const int e = i / C_INST, c = i % C_INST;
        const float cnv = counts[b * C_INST + c];
        mu_l[e][c] = (cnv > 0.f) ? sums[((size_t)b * C_INST + c) * E_DIM + e] / cnv : 0.f;
    }
    __syncthreads();

    const float4* __restrict__ src4 = (const float4*)(input + (size_t)b * E_DIM * HW_N);
    const int4*   __restrict__ tgt4 = (const int4*)(target + (size_t)b * HW_N);

    const int g = blockIdx.x * 256 + tid;      // 256 blocks * 256 thr = 65536 groups
    const int4 lab4 = tgt4[g];
    const int* lp = &lab4.x;

    float d2[4] = {0.f, 0.f, 0.f, 0.f};
    #pragma unroll
    for (int e = 0; e < E_DIM; ++e) {
        const float4 xv = src4[(size_t)e * (HW_N / 4) + g];
        const float* xp = &xv.x;
        #pragma unroll
        for (int p = 0; p < 4; ++p) {
            const float diff = xp[p] - mu_l[e][lp[p]];
            d2[p] = fmaf(diff, diff, d2[p]);
        }
    }

    float h2[4];
    #pragma unroll
    for (int p = 0; p < 4; ++p) {
        const float h = fmaxf(sqrtf(d2[p]) - DELTA_VAR, 0.f);
        h2[p] = h * h;
    }

    float vacc[C_INST];
    #pragma unroll
    for (int c = 0; c < C_INST; ++c) vacc[c] = 0.f;
    #pragma unroll
    for (int p = 0; p < 4; ++p) {
        const int lab = lp[p];
        #pragma unroll
        for (int c = 0; c < C_INST; ++c) {
            const float sel = (lab == c) ? 1.f : 0.f;
            vacc[c] = fmaf(sel, h2[p], vacc[c]);
        }
    }

    #pragma unroll
    for (int c = 0; c < C_INST; ++c)
        #pragma unroll
        for (int m = 1; m < 64; m <<= 1)
            vacc[c] += __shfl_xor(vacc[c], m, 64);

    __shared__ float redv[4][C_INST];
    if (lane == 0) {
        #pragma unroll
        for (int c = 0; c < C_INST; ++c) redv[wv][c] = vacc[c];
    }
    __syncthreads();
    if (tid < C_INST) {
        const float s = redv[0][tid] + redv[1][tid] + redv[2][tid] + redv[3][tid];
        unsafeAtomicAdd(&vars[b * C_INST + tid], s);
    }
}

// ---------------------------------------------------------------------------
// Final: variance + pairwise distance + regularizer -> scalar loss.
// ---------------------------------------------------------------------------
__global__ __launch_bounds__(256) void final_kernel(
    const float* __restrict__ sums, const float* __restrict__ counts,
    const float* __restrict__ vars, float* __restrict__ out)
{
    __shared__ float mu[B_SZ][C_INST][E_DIM];
    __shared__ float red[256];
    const int tid = threadIdx.x;

    for (int i = tid; i < B_SZ * C_INST * E_DIM; i += 256) {
        const int bc = i / E_DIM;
        const float cnv = counts[bc];
        ((float*)mu)[i] = (cnv > 0.f) ? sums[i] / cnv : 0.f;
    }
    __syncthreads();

    float acc = 0.f;
    for (int i = tid; i < B_SZ * C_INST; i += 256) {
        const int b = i / C_INST, c = i % C_INST;
        const float cnv = counts[i];
        const float var = (cnv > 0.f) ? vars[i] / cnv : 0.f;
        float n2 = 0.f;
        #pragma unroll
        for (int e = 0; e < E_DIM; ++e) n2 += mu[b][c][e] * mu[b][c][e];
        acc += (ALPHA_W * var + GAMMA_W * sqrtf(n2)) * (1.0f / (B_SZ * C_INST));
    }
    for (int i = tid; i < B_SZ * C_INST * C_INST; i += 256) {
        const int b  = i / (C_INST * C_INST);
        const int r  = i % (C_INST * C_INST);
        const int c1 = r / C_INST, c2 = r % C_INST;
        if (c1 != c2) {
            float d2 = 0.f;
            #pragma unroll
            for (int e = 0; e < E_DIM; ++e) {
                const float d = mu[b][c1][e] - mu[b][c2][e];
                d2 += d * d;
            }
            const float h = fmaxf(2.0f * DELTA_DIST - sqrtf(d2), 0.f);
            acc += BETA_W * h * h * (1.0f / (B_SZ * C_INST * (C_INST - 1)));
        }
    }

    red[tid] = acc;
    __syncthreads();
    for (int s = 128; s > 0; s >>= 1) {
        if (tid < s) red[tid] += red[tid + s];
        __syncthreads();
    }
    if (tid == 0) out[0] = red[0];
}

extern "C" void kernel_launch(void* const* d_in, const int* in_sizes, int n_in,
                              void* d_out, int out_size, void* d_ws, size_t ws_size,
                              hipStream_t stream)
{
    const float* input  = (const float*)d_in[0];
    const int*   target = (const int*)d_in[1];

    float* sums   = (float*)d_ws;                       // B*C*E
    float* counts = sums + B_SZ * C_INST * E_DIM;       // B*C
    float* vars   = counts + B_SZ * C_INST;             // B*C
    const size_t ws_bytes =
        (size_t)(B_SZ * C_INST * E_DIM + 2 * B_SZ * C_INST) * sizeof(float);
    hipMemsetAsync(d_ws, 0, ws_bytes, stream);

    pass1_kernel<<<dim3(P1_BLOCKS, 8, B_SZ), 256, 0, stream>>>(input, target, sums, counts);
    pass2_kernel<<<dim3(P1_GROUPS / 256, B_SZ), 256, 0, stream>>>(input, target, sums, counts, vars);
    final_kernel<<<1, 256, 0, stream>>>(sums, counts, vars, (float*)d_out);
}

// Round 4
// 131.872 us; speedup vs baseline: 2.4896x; 2.4896x over previous
//
#include <hip/hip_runtime.h>
#include <cstdint>

#define B_SZ   4
#define E_DIM  16
#define C_INST 24
#define HW_N   262144          // 512*512
#define NG     (HW_N / 4)      // 65536 float4 pixel-groups per (b, e)

#define DELTA_VAR  0.75f
#define DELTA_DIST 2.0f
#define ALPHA_W 1.0f
#define BETA_W  1.0f
#define GAMMA_W 0.001f

#define P1_NB   16                       // blocks per (e, b) column
#define P1_ITER (NG / (P1_NB * 256))     // 16
#define BUK_STRIDE 25                    // 24 classes + 1 pad word (bank spread)

// ---------------------------------------------------------------------------
// Pass 1: segment sums via LANE-PRIVATE LDS buckets. buk[tid][c] += x needs
// no atomics (row私有 per thread) and no compare chain: 2 LDS ops per
// (pixel,e) instead of ~30 VALU ops. grid.y==E_DIM is the count plane
// (labels only, accumulates 1.0). Epilogue: 3 waves column-reduce 256 rows,
// 3-step shfl within 8-lane groups, 24 global atomics per block.
// VGPR ~32 (NO launch_bounds occupancy cap — R3's spill lesson).
// ---------------------------------------------------------------------------
__global__ __launch_bounds__(256) void pass1_kernel(
    const float* __restrict__ input, const int* __restrict__ target,
    float* __restrict__ sums, float* __restrict__ counts)
{
    __shared__ float buk[256][BUK_STRIDE];
    const int tid = threadIdx.x;
    const int eg  = blockIdx.y;           // 0..15 = embedding dim, 16 = counts
    const int b   = blockIdx.z;

    float* __restrict__ myrow = &buk[tid][0];
    #pragma unroll
    for (int j = 0; j < C_INST; ++j) myrow[j] = 0.f;   // own row: no sync needed

    const int4* __restrict__ tgt4 = (const int4*)(target + (size_t)b * HW_N);
    const int gbase = blockIdx.x * 256 * P1_ITER + tid;

    if (eg < E_DIM) {
        const float4* __restrict__ src4 =
            (const float4*)(input + ((size_t)b * E_DIM + eg) * HW_N);
        int4   lab = tgt4[gbase];
        float4 x   = src4[gbase];
        #pragma unroll
        for (int it = 0; it < P1_ITER; ++it) {
            const int4   labc = lab;
            const float4 xc   = x;
            if (it + 1 < P1_ITER) {            // register double-buffer prefetch
                lab = tgt4[gbase + (it + 1) * 256];
                x   = src4[gbase + (it + 1) * 256];
            }
            myrow[labc.x] += xc.x;
            myrow[labc.y] += xc.y;
            myrow[labc.z] += xc.z;
            myrow[labc.w] += xc.w;
        }
    } else {
        // count plane: labels only
        #pragma unroll
        for (int it = 0; it < P1_ITER; ++it) {
            const int4 labc = tgt4[gbase + it * 256];
            myrow[labc.x] += 1.f;
            myrow[labc.y] += 1.f;
            myrow[labc.z] += 1.f;
            myrow[labc.w] += 1.f;
        }
    }
    __syncthreads();

    // reduce 256 rows -> 24 class sums; 8 threads per class
    if (tid < 8 * C_INST) {
        const int c  = tid >> 3;
        const int r0 = tid & 7;
        float s = 0.f;
        #pragma unroll
        for (int i = 0; i < 32; ++i) s += buk[8 * i + r0][c];
        s += __shfl_xor(s, 1, 64);
        s += __shfl_xor(s, 2, 64);
        s += __shfl_xor(s, 4, 64);
        if (r0 == 0) {
            if (eg < E_DIM)
                unsafeAtomicAdd(&sums[((size_t)b * E_DIM + eg) * C_INST + c], s);
            else
                unsafeAtomicAdd(&counts[b * C_INST + c], s);
        }
    }
}

// ---------------------------------------------------------------------------
// Pass 2: variance term only, as ONE scalar: sum of h^2 / cnt[lab] over all
// pixels/batches. mu rows in LDS [c][20] (16B-aligned rows, stride breaks
// power-of-2 banks). One float4 pixel-group per thread, scalar butterfly,
// one atomic per block.
// ---------------------------------------------------------------------------
__global__ __launch_bounds__(256) void pass2_kernel(
    const float* __restrict__ input, const int* __restrict__ target,
    const float* __restrict__ sums, const float* __restrict__ counts,
    float* __restrict__ loss_acc)
{
    __shared__ float mu_l[C_INST][20];
    __shared__ float w_l[C_INST];
    __shared__ float redw[4];
    const int tid  = threadIdx.x;
    const int lane = tid & 63;
    const int wv   = tid >> 6;
    const int b    = blockIdx.y;

    if (tid < C_INST) {
        const float cv = counts[b * C_INST + tid];
        w_l[tid] = (cv > 0.f) ? 1.f / cv : 0.f;
    }
    __syncthreads();
    for (int i = tid; i < E_DIM * C_INST; i += 256) {
        const int e = i / C_INST, c = i % C_INST;
        mu_l[c][e] = sums[((size_t)b * E_DIM + e) * C_INST + c] * w_l[c];
    }
    __syncthreads();

    const int g = blockIdx.x * 256 + tid;   // 256 blocks/batch * 256 = 65536
    const int4 lab4 = ((const int4*)(target + (size_t)b * HW_N))[g];
    const int lp[4] = {lab4.x, lab4.y, lab4.z, lab4.w};

    const float4* __restrict__ src4 = (const float4*)(input + (size_t)b * E_DIM * HW_N);
    float xs[E_DIM * 4];
    #pragma unroll
    for (int e = 0; e < E_DIM; ++e)
        ((float4*)xs)[e] = src4[(size_t)e * NG + g];

    float vloc = 0.f;
    #pragma unroll
    for (int p = 0; p < 4; ++p) {
        const int c = lp[p];
        float d2 = 0.f;
        #pragma unroll
        for (int e = 0; e < E_DIM; ++e) {
            const float diff = xs[e * 4 + p] - mu_l[c][e];
            d2 = fmaf(diff, diff, d2);
        }
        const float h = fmaxf(sqrtf(d2) - DELTA_VAR, 0.f);
        vloc = fmaf(h * h, w_l[c], vloc);
    }

    #pragma unroll
    for (int m = 1; m < 64; m <<= 1) vloc += __shfl_xor(vloc, m, 64);
    if (lane == 0) redw[wv] = vloc;
    __syncthreads();
    if (tid == 0)
        unsafeAtomicAdd(loss_acc, redw[0] + redw[1] + redw[2] + redw[3]);
}

// ---------------------------------------------------------------------------
// Final: pairwise distance + regularizer + variance scalar -> loss.
// ---------------------------------------------------------------------------
__global__ __launch_bounds__(256) void final_kernel(
    const float* __restrict__ sums, const float* __restrict__ counts,
    const float* __restrict__ loss_acc, float* __restrict__ out)
{
    __shared__ float mu[B_SZ][C_INST][E_DIM];
    __shared__ float red[256];
    const int tid = threadIdx.x;

    for (int i = tid; i < B_SZ * C_INST * E_DIM; i += 256) {
        const int b = i / (C_INST * E_DIM);
        const int r = i % (C_INST * E_DIM);
        const int e = r / C_INST, c = r % C_INST;   // iterate in sums' layout
        const float cv = counts[b * C_INST + c];
        mu[b][c][e] = (cv > 0.f)
            ? sums[((size_t)b * E_DIM + e) * C_INST + c] / cv : 0.f;
    }
    __syncthreads();

    float acc = 0.f;
    // regularizer
    for (int i = tid; i < B_SZ * C_INST; i += 256) {
        const int b = i / C_INST, c = i % C_INST;
        float n2 = 0.f;
        #pragma unroll
        for (int e = 0; e < E_DIM; ++e) n2 += mu[b][c][e] * mu[b][c][e];
        acc += GAMMA_W * sqrtf(n2) * (1.0f / (B_SZ * C_INST));
    }
    // pairwise repulsion
    for (int i = tid; i < B_SZ * C_INST * C_INST; i += 256) {
        const int b  = i / (C_INST * C_INST);
        const int r  = i % (C_INST * C_INST);
        const int c1 = r / C_INST, c2 = r % C_INST;
        if (c1 != c2) {
            float d2 = 0.f;
            #pragma unroll
            for (int e = 0; e < E_DIM; ++e) {
                const float d = mu[b][c1][e] - mu[b][c2][e];
                d2 += d * d;
            }
            const float h = fmaxf(2.0f * DELTA_DIST - sqrtf(d2), 0.f);
            acc += BETA_W * h * h * (1.0f / (B_SZ * C_INST * (C_INST - 1)));
        }
    }

    red[tid] = acc;
    __syncthreads();
    for (int s = 128; s > 0; s >>= 1) {
        if (tid < s) red[tid] += red[tid + s];
        __syncthreads();
    }
    if (tid == 0)
        out[0] = red[0] + ALPHA_W * loss_acc[0] * (1.0f / (B_SZ * C_INST));
}

extern "C" void kernel_launch(void* const* d_in, const int* in_sizes, int n_in,
                              void* d_out, int out_size, void* d_ws, size_t ws_size,
                              hipStream_t stream)
{
    const float* input  = (const float*)d_in[0];
    const int*   target = (const int*)d_in[1];

    float* sums     = (float*)d_ws;                         // B*E*C  (layout [b][e][c])
    float* counts   = sums + B_SZ * E_DIM * C_INST;         // B*C
    float* loss_acc = counts + B_SZ * C_INST;               // 1
    const size_t ws_bytes =
        (size_t)(B_SZ * E_DIM * C_INST + B_SZ * C_INST + 1) * sizeof(float);
    hipMemsetAsync(d_ws, 0, ws_bytes, stream);

    pass1_kernel<<<dim3(P1_NB, E_DIM + 1, B_SZ), 256, 0, stream>>>(input, target, sums, counts);
    pass2_kernel<<<dim3(NG / 256, B_SZ), 256, 0, stream>>>(input, target, sums, counts, loss_acc);
    final_kernel<<<1, 256, 0, stream>>>(sums, counts, loss_acc, (float*)d_out);
}